// Round 3
// baseline (158.445 us; speedup 1.0000x reference)
//
#include <hip/hip_runtime.h>

#define H_IMG 1080
#define W_IMG 1920
#define HW_PIX (H_IMG * W_IMG)
#define GY 16
#define GX 16
#define GL 8
#define CF 12          // floats per grid cell
#define PPB 128        // pixels per block; 1920 = 15*128
#define TPB (PPB * 3)  // 384 threads: thread t -> pixel t/3, affine row t%3

// Store-coalescing-first design: thread t owns (pixel k=t/3, affine row c=t%3).
// Its 4-float affine row lands at float4 index p0*3+t -> consecutive lanes write
// consecutive 16B (full-line packed stores, no partial-line amplification).
// res_rgb likewise: thread t writes res float #(p0*3+t), coalesced dwords.
// Grid slab (3 x-cells x 8 z x 12ch, y-lerped) staged in LDS: 1.15 KB.
__global__ __launch_bounds__(TPB) void bg_kernel(
    const float* __restrict__ rgb,    // (3, H, W)
    const float* __restrict__ grids,  // (NUM, 16, 16, 8, 12)
    const int* __restrict__ idxp,
    float* __restrict__ out)          // [affine HW*12 | res HW*3]
{
    __shared__ float4 sg[72];         // [xi(3)][z(8)][c4(3)]

    const int tid = threadIdx.x;
    const int y = blockIdx.y;
    const int xbase = blockIdx.x * PPB;

    const float* grid = grids + (size_t)idxp[0] * (GY * GX * GL * CF);

    // row-uniform y interpolation factors
    float gyv = (float)y * (15.0f / 1079.0f);
    float fy = floorf(gyv);
    float wy = gyv - fy;
    int y0 = min(max((int)fy, 0), GY - 1);
    int y1 = min(y0 + 1, GY - 1);

    // block-uniform first x-cell; 128-px span touches at most 3 cells
    int xc0 = (int)floorf((float)xbase * (15.0f / 1919.0f));

    if (tid < 72) {
        int xi  = tid / 24;
        int rem = tid - xi * 24;
        int z   = rem / 3;
        int c4  = rem - z * 3;
        int xc  = min(xc0 + xi, GX - 1);
        const float4* c0 = (const float4*)(grid + (size_t)((y0 * GX + xc) * GL + z) * CF) + c4;
        const float4* c1 = (const float4*)(grid + (size_t)((y1 * GX + xc) * GL + z) * CF) + c4;
        float4 a = *c0, b = *c1;
        float wy0 = 1.0f - wy;
        float4 rr;
        rr.x = wy0 * a.x + wy * b.x;
        rr.y = wy0 * a.y + wy * b.y;
        rr.z = wy0 * a.z + wy * b.z;
        rr.w = wy0 * a.w + wy * b.w;
        sg[tid] = rr;
    }
    __syncthreads();

    const int k = tid / 3;            // pixel within block [0,128)
    const int c = tid - k * 3;        // affine row [0,3)
    const int x = xbase + k;
    const int p = y * W_IMG + x;

    float r = rgb[p];
    float g = rgb[HW_PIX + p];
    float b = rgb[2 * HW_PIX + p];

    float gray = 0.299f * r + 0.587f * g + 0.114f * b;

    float gxv = (float)x * (15.0f / 1919.0f);
    float fx = floorf(gxv), wx = gxv - fx;
    float gz = fminf(fmaxf(gray, 0.0f), 1.0f) * 7.0f;
    float fz = floorf(gz), wz = gz - fz;

    int x0g = min(max((int)fx, 0), GX - 1);
    int x1g = min(x0g + 1, GX - 1);
    int xi0 = x0g - xc0;              // in [0,2]
    int xi1 = x1g - xc0;              // in [0,2]
    int z0 = min(max((int)fz, 0), GL - 1);
    int z1 = min(z0 + 1, GL - 1);

    float w00 = (1.0f - wx) * (1.0f - wz);
    float w01 = (1.0f - wx) * wz;
    float w10 = wx * (1.0f - wz);
    float w11 = wx * wz;

    float4 A = sg[(xi0 * GL + z0) * 3 + c];
    float4 B = sg[(xi0 * GL + z1) * 3 + c];
    float4 C = sg[(xi1 * GL + z0) * 3 + c];
    float4 D = sg[(xi1 * GL + z1) * 3 + c];

    float4 acc;
    acc.x = fmaf(w00, A.x, fmaf(w01, B.x, fmaf(w10, C.x, w11 * D.x)));
    acc.y = fmaf(w00, A.y, fmaf(w01, B.y, fmaf(w10, C.y, w11 * D.y)));
    acc.z = fmaf(w00, A.z, fmaf(w01, B.z, fmaf(w10, C.z, w11 * D.z)));
    acc.w = fmaf(w00, A.w, fmaf(w01, B.w, fmaf(w10, C.w, w11 * D.w)));

    const size_t base3 = (size_t)(y * W_IMG + xbase) * 3;  // float4s / floats

    // affine: float4 index base3 + t -> 16B/lane, consecutive -> full lines
    ((float4*)out)[base3 + tid] = acc;

    // res row c for pixel k: coalesced dword at float index HW*12 + base3 + t
    float res = fmaf(acc.x, r, fmaf(acc.y, g, fmaf(acc.z, b, acc.w)));
    out[(size_t)HW_PIX * 12 + base3 + tid] = res;
}

extern "C" void kernel_launch(void* const* d_in, const int* in_sizes, int n_in,
                              void* d_out, int out_size, void* d_ws, size_t ws_size,
                              hipStream_t stream) {
    const float* rgb   = (const float*)d_in[0];
    const float* grids = (const float*)d_in[1];
    const int*   idx   = (const int*)d_in[2];
    float*       out   = (float*)d_out;

    dim3 grid(W_IMG / PPB, H_IMG);   // (15, 1080)
    dim3 block(TPB);                 // 384
    bg_kernel<<<grid, block, 0, stream>>>(rgb, grids, idx, out);
}